// Round 1
// baseline (453.592 us; speedup 1.0000x reference)
//
#include <hip/hip_runtime.h>
#include <cstdint>
#include <cstddef>

typedef __attribute__((ext_vector_type(8))) short bf16x8;
typedef __attribute__((ext_vector_type(4))) float f32x4;

#define CSCALE 0.04508687625f  /* (1/sqrt(1024)) * log2(e) */

__device__ __forceinline__ void gload_lds16(const void* g, void* l) {
  __builtin_amdgcn_global_load_lds(
      (const __attribute__((address_space(1))) unsigned int*)g,
      (__attribute__((address_space(3))) unsigned int*)l, 16, 0, 0);
}

__device__ __forceinline__ unsigned short f2bf(float f) {
  unsigned int u = __float_as_uint(f);
  return (unsigned short)((u + 0x7FFFu + ((u >> 16) & 1u)) >> 16);
}

// ---------------------------------------------------------------- convert
__global__ void cvt_kernel(const float* __restrict__ in,
                           unsigned short* __restrict__ out, int n8) {
  int i = blockIdx.x * blockDim.x + threadIdx.x;
  if (i >= n8) return;
  const float4* p = (const float4*)in + (size_t)i * 2;
  float4 a = p[0], b = p[1];
  float vals[8] = {a.x, a.y, a.z, a.w, b.x, b.y, b.z, b.w};
  union { unsigned short u[8]; uint4 v; } r;
#pragma unroll
  for (int j = 0; j < 8; ++j) r.u[j] = f2bf(vals[j]);
  ((uint4*)out)[i] = r.v;
}

// ---------------------------------------------------------------- GEMM
// C[M][N] = A[M][K=1024] * B[N][K=1024]^T, all bf16, fp32 accum.
// m97 structure: 128x128 tile, BK=32, 4 waves (2x2 of 64x64), dbuf LDS,
// global_load_lds width 16, raw barrier + vmcnt(0) per K-step.
__global__ __launch_bounds__(256) void gemm_bt(
    const unsigned short* __restrict__ A, const unsigned short* __restrict__ B,
    unsigned short* __restrict__ C, int ldc) {
  __shared__ unsigned short As[2][4096];
  __shared__ unsigned short Bs[2][4096];
  const int tid = threadIdx.x, w = tid >> 6, lane = tid & 63;
  const int l15 = lane & 15, g = lane >> 4;
  const int bm = blockIdx.x, bn = blockIdx.y;
  const int wm = w >> 1, wn = w & 1;
  f32x4 acc[4][4] = {};

  auto stage = [&](int buf, int k0) {
#pragma unroll
    for (int oi = 0; oi < 2; ++oi) {
      int o = w + oi * 4;               // block-level op 0..7
      int chunk = o * 64 + lane;        // 16B chunk index in tile
      int row = chunk >> 2, c8 = chunk & 3;
      gload_lds16(A + (size_t)(bm * 128 + row) * 1024 + k0 + c8 * 8,
                  &As[buf][o * 512]);
      gload_lds16(B + (size_t)(bn * 128 + row) * 1024 + k0 + c8 * 8,
                  &Bs[buf][o * 512]);
    }
  };

  stage(0, 0);
  asm volatile("s_waitcnt vmcnt(0)" ::: "memory");
  __builtin_amdgcn_s_barrier();

  for (int t = 0; t < 32; ++t) {
    int buf = t & 1;
    if (t < 31) stage(buf ^ 1, (t + 1) * 32);
    bf16x8 af[4], bfr[4];
#pragma unroll
    for (int mt = 0; mt < 4; ++mt)
      af[mt] = *(const bf16x8*)&As[buf][(wm * 64 + mt * 16 + l15) * 32 + g * 8];
#pragma unroll
    for (int nt = 0; nt < 4; ++nt)
      bfr[nt] = *(const bf16x8*)&Bs[buf][(wn * 64 + nt * 16 + l15) * 32 + g * 8];
#pragma unroll
    for (int mt = 0; mt < 4; ++mt)
#pragma unroll
      for (int nt = 0; nt < 4; ++nt)
        acc[mt][nt] = __builtin_amdgcn_mfma_f32_16x16x32_bf16(
            af[mt], bfr[nt], acc[mt][nt], 0, 0, 0);
    asm volatile("s_waitcnt vmcnt(0)" ::: "memory");
    __builtin_amdgcn_s_barrier();
  }

#pragma unroll
  for (int mt = 0; mt < 4; ++mt) {
#pragma unroll
    for (int r = 0; r < 4; ++r) {
      int row = bm * 128 + wm * 64 + mt * 16 + g * 4 + r;
      unsigned short* Cp = C + (size_t)row * ldc + bn * 128 + wn * 64 + l15;
#pragma unroll
      for (int nt = 0; nt < 4; ++nt) Cp[nt * 16] = f2bf(acc[mt][nt][r]);
    }
  }
}

// ---------------------------------------------------------------- attention
// QK: [8192][2048] bf16 (cols 0..1023 = Q, 1024..2047 = K), Vt: [1024][8192].
// QBLK=16, KVBLK=128, 8 waves. Q in regs; K/V streamed from global.
__global__ __launch_bounds__(512) void attn_kernel(
    const unsigned short* __restrict__ QK, const unsigned short* __restrict__ Vt,
    float* __restrict__ Out) {
  __shared__ float red_max[16][8];
  __shared__ float red_sum[16][8];
  __shared__ unsigned short P_lds[16][136];  // +8 pad: conflict-free b128 reads

  const int tid = threadIdx.x, w = tid >> 6, lane = tid & 63;
  const int l15 = lane & 15, g = lane >> 4;

  for (int it = 0; it < 2; ++it) {
    int j = (it == 0) ? (int)blockIdx.x : (511 - (int)blockIdx.x);
    int qt = 127 - (j >> 2);  // snake pairing: balanced causal work
    int b = j & 3;
    int qbase = qt * 16;

    // Q fragments for all 32 K-steps (rows l15, k-chunk g*8): 128 VGPRs.
    const unsigned short* Qp =
        QK + (size_t)(b * 2048 + qbase + l15) * 2048 + g * 8;
    bf16x8 qf[32];
#pragma unroll
    for (int kk = 0; kk < 32; ++kk) qf[kk] = *(const bf16x8*)(Qp + kk * 32);

    f32x4 o[8] = {};
    float m[4] = {-__builtin_inff(), -__builtin_inff(), -__builtin_inff(),
                  -__builtin_inff()};
    float lsum[4] = {0.f, 0.f, 0.f, 0.f};

    int kvend = qbase + 16;
    int ntile = (kvend + 127) >> 7;
    for (int t = 0; t < ntile; ++t) {
      int kvbase = t << 7;
      // ---- S = Q @ K^T for this wave's 16-kv strip (full D=1024) ----
      f32x4 s = {0.f, 0.f, 0.f, 0.f};
      const unsigned short* Kp =
          QK + (size_t)(b * 2048 + kvbase + w * 16 + l15) * 2048 + 1024 + g * 8;
#pragma unroll
      for (int c = 0; c < 4; ++c) {
        bf16x8 kf[8];
#pragma unroll
        for (int u = 0; u < 8; ++u)
          kf[u] = *(const bf16x8*)(Kp + (c * 8 + u) * 32);
#pragma unroll
        for (int u = 0; u < 8; ++u)
          s = __builtin_amdgcn_mfma_f32_16x16x32_bf16(qf[c * 8 + u], kf[u], s,
                                                      0, 0, 0);
      }
      // ---- causal mask + scale (base-2 folded) ----
      int kv = kvbase + w * 16 + l15;
      float sv[4];
#pragma unroll
      for (int r = 0; r < 4; ++r) {
        int q = qbase + g * 4 + r;
        sv[r] = (kv <= q) ? s[r] * CSCALE : -__builtin_inff();
      }
      // ---- wave-local row max (16 lanes share a row) ----
      float lmax[4];
#pragma unroll
      for (int r = 0; r < 4; ++r) {
        float mx = sv[r];
        mx = fmaxf(mx, __shfl_xor(mx, 1));
        mx = fmaxf(mx, __shfl_xor(mx, 2));
        mx = fmaxf(mx, __shfl_xor(mx, 4));
        mx = fmaxf(mx, __shfl_xor(mx, 8));
        lmax[r] = mx;
      }
      if (l15 == 0) {
#pragma unroll
        for (int r = 0; r < 4; ++r) red_max[g * 4 + r][w] = lmax[r];
      }
      __syncthreads();
      float al[4], p[4];
#pragma unroll
      for (int r = 0; r < 4; ++r) {
        float mm = m[r];
#pragma unroll
        for (int ww = 0; ww < 8; ++ww) mm = fmaxf(mm, red_max[g * 4 + r][ww]);
        al[r] = exp2f(m[r] - mm);
        p[r] = exp2f(sv[r] - mm);
        m[r] = mm;
      }
      // ---- wave-local row sum + P export ----
      float ls[4];
#pragma unroll
      for (int r = 0; r < 4; ++r) {
        float ss = p[r];
        ss += __shfl_xor(ss, 1);
        ss += __shfl_xor(ss, 2);
        ss += __shfl_xor(ss, 4);
        ss += __shfl_xor(ss, 8);
        ls[r] = ss;
      }
      if (l15 == 0) {
#pragma unroll
        for (int r = 0; r < 4; ++r) red_sum[g * 4 + r][w] = ls[r];
      }
#pragma unroll
      for (int r = 0; r < 4; ++r) P_lds[g * 4 + r][w * 16 + l15] = f2bf(p[r]);
      __syncthreads();
#pragma unroll
      for (int r = 0; r < 4; ++r) {
        float tot = 0.f;
#pragma unroll
        for (int ww = 0; ww < 8; ++ww) tot += red_sum[g * 4 + r][ww];
        lsum[r] = lsum[r] * al[r] + tot;
      }
      // ---- rescale O, then O += P @ V (wave's 128 d-columns) ----
#pragma unroll
      for (int nt = 0; nt < 8; ++nt)
#pragma unroll
        for (int r = 0; r < 4; ++r) o[nt][r] *= al[r];
      bf16x8 pf[4];
#pragma unroll
      for (int kk = 0; kk < 4; ++kk)
        pf[kk] = *(const bf16x8*)&P_lds[l15][kk * 32 + g * 8];
      const unsigned short* Vp =
          Vt + (size_t)(w * 128 + l15) * 8192 + b * 2048 + kvbase + g * 8;
#pragma unroll
      for (int nt = 0; nt < 8; ++nt) {
        bf16x8 vf[4];
#pragma unroll
        for (int kk = 0; kk < 4; ++kk)
          vf[kk] = *(const bf16x8*)(Vp + (size_t)nt * 16 * 8192 + kk * 32);
#pragma unroll
        for (int kk = 0; kk < 4; ++kk)
          o[nt] = __builtin_amdgcn_mfma_f32_16x16x32_bf16(pf[kk], vf[kk],
                                                          o[nt], 0, 0, 0);
      }
    }
    // ---- epilogue: Out = O / l ----
    float inv[4];
#pragma unroll
    for (int r = 0; r < 4; ++r) inv[r] = 1.0f / lsum[r];
    float* Op = Out + (size_t)(b * 2048 + qbase + g * 4) * 1024 + w * 128 + l15;
#pragma unroll
    for (int nt = 0; nt < 8; ++nt)
#pragma unroll
      for (int r = 0; r < 4; ++r)
        Op[(size_t)r * 1024 + nt * 16] = o[nt][r] * inv[r];
  }
}

// ---------------------------------------------------------------- launch
extern "C" void kernel_launch(void* const* d_in, const int* in_sizes, int n_in,
                              void* d_out, int out_size, void* d_ws,
                              size_t ws_size, hipStream_t stream) {
  const float* x = (const float*)d_in[0];
  const float* Wq = (const float*)d_in[1];
  const float* Wk = (const float*)d_in[2];
  const float* Wv = (const float*)d_in[3];
  unsigned short* ws = (unsigned short*)d_ws;
  // ws layout (elements): xb 8M | Wqk 2M | Wv 1M | QK 16M | Vt 8M = 70 MB
  unsigned short* xb = ws;
  unsigned short* Wqk = ws + (size_t)(8u << 20);
  unsigned short* Wvb = ws + (size_t)(10u << 20);
  unsigned short* QKb = ws + (size_t)(11u << 20);
  unsigned short* Vtb = ws + (size_t)(27u << 20);

  cvt_kernel<<<4096, 256, 0, stream>>>(x, xb, 1048576);
  cvt_kernel<<<512, 256, 0, stream>>>(Wq, Wqk, 131072);
  cvt_kernel<<<512, 256, 0, stream>>>(Wk, Wqk + (size_t)(1u << 20), 131072);
  cvt_kernel<<<512, 256, 0, stream>>>(Wv, Wvb, 131072);
  // QK = xb @ [Wq;Wk]^T : [8192 x 2048]
  gemm_bt<<<dim3(64, 16), 256, 0, stream>>>(xb, Wqk, QKb, 2048);
  // Vt = Wv @ xb^T : [1024 x 8192]
  gemm_bt<<<dim3(8, 64), 256, 0, stream>>>(Wvb, xb, Vtb, 8192);
  attn_kernel<<<256, 512, 0, stream>>>(QKb, Vtb, (float*)d_out);
}

// Round 2
// 286.741 us; speedup vs baseline: 1.5819x; 1.5819x over previous
//
#include <hip/hip_runtime.h>
#include <cstdint>
#include <cstddef>

typedef __attribute__((ext_vector_type(8))) short bf16x8;
typedef __attribute__((ext_vector_type(4))) float f32x4;

#define CSCALE 0.045084220027780106f /* log2(e) / sqrt(1024) */

__device__ __forceinline__ void gload_lds16(const void* g, void* l) {
  __builtin_amdgcn_global_load_lds(
      (const __attribute__((address_space(1))) unsigned int*)g,
      (__attribute__((address_space(3))) unsigned int*)l, 16, 0, 0);
}

__device__ __forceinline__ unsigned short f2bf(float f) {
  unsigned int u = __float_as_uint(f);
  return (unsigned short)((u + 0x7FFFu + ((u >> 16) & 1u)) >> 16);
}

__device__ __forceinline__ float bf2f(unsigned short u) {
  return __uint_as_float((unsigned int)u << 16);
}

// ---------------------------------------------------------------- convert
__global__ void cvt_kernel(const float* __restrict__ in,
                           unsigned short* __restrict__ out, int n8) {
  int i = blockIdx.x * blockDim.x + threadIdx.x;
  if (i >= n8) return;
  const float4* p = (const float4*)in + (size_t)i * 2;
  float4 a = p[0], b = p[1];
  float vals[8] = {a.x, a.y, a.z, a.w, b.x, b.y, b.z, b.w};
  union { unsigned short u[8]; uint4 v; } r;
#pragma unroll
  for (int j = 0; j < 8; ++j) r.u[j] = f2bf(vals[j]);
  ((uint4*)out)[i] = r.v;
}

// ---------------------------------------------------------------- GEMM
// m97 structure: 128x128 tile, BK=32, 4 waves (2x2 of 64x64), dbuf LDS,
// global_load_lds width 16, raw barrier + vmcnt(0) per K-step.
// C = A * B^T (both operands row-major over the K axis).
// MODE 0: proj  A=xb[8192][1024]   B=Wqk[2048][1024]  C=QK bf16 [8192][2048]
// MODE 1: Vt    A=Wv[1024][1024]   B=xb[8192][1024]   C=Vt bf16 [1024][8192]
// MODE 2: S     A=QK(Q)[..][2048]  B=QK+1024(K)       C=S  bf16 [8192][2048]
//               grid(16,16,4), lower-triangle tiles only (causal)
// MODE 3: PV    A=P[8192][2048]    B=Vt[1024][8192]   C=Out f32 [8192][1024]
//               variable ksteps=(qt+1)*4, longest-first, B col offset b*2048
template <int MODE>
__global__ __launch_bounds__(256) void gemm_k(
    const unsigned short* __restrict__ A, const unsigned short* __restrict__ B,
    void* __restrict__ Cv) {
  constexpr int LDA = (MODE <= 1) ? 1024 : 2048;
  constexpr int LDB = (MODE <= 1) ? 1024 : (MODE == 2 ? 2048 : 8192);
  constexpr int LDC =
      (MODE == 0) ? 2048 : (MODE == 1 ? 8192 : (MODE == 2 ? 2048 : 1024));

  int arow, brow, ksteps = 32, kb = 0;
  size_t cbase;
  if constexpr (MODE == 0 || MODE == 1) {
    arow = blockIdx.x * 128;
    brow = blockIdx.y * 128;
    cbase = (size_t)arow * LDC + blockIdx.y * 128;
  } else if constexpr (MODE == 2) {
    int i = blockIdx.x, j = blockIdx.y, b = blockIdx.z;
    if (j > i) return;  // causal: upper tiles never read downstream
    arow = b * 2048 + i * 128;
    brow = b * 2048 + j * 128;
    cbase = (size_t)(b * 2048 + i * 128) * LDC + j * 128;
  } else {
    int bm = blockIdx.x;
    int b = bm >> 4, qt = 15 - (bm & 15);  // longest K-extent first
    arow = b * 2048 + qt * 128;
    brow = blockIdx.y * 128;
    kb = b * 2048;
    ksteps = (qt + 1) * 4;
    cbase = (size_t)(b * 2048 + qt * 128) * LDC + blockIdx.y * 128;
  }

  __shared__ unsigned short As[2][4096];
  __shared__ unsigned short Bs[2][4096];
  const int tid = threadIdx.x, w = tid >> 6, lane = tid & 63;
  const int l15 = lane & 15, g = lane >> 4;
  const int wm = w >> 1, wn = w & 1;
  f32x4 acc[4][4] = {};

  auto stage = [&](int buf, int k0) {
#pragma unroll
    for (int oi = 0; oi < 2; ++oi) {
      int o = w + oi * 4;         // block-level op 0..7
      int chunk = o * 64 + lane;  // 16B chunk index in tile
      int row = chunk >> 2, c8 = chunk & 3;
      gload_lds16(A + (size_t)(arow + row) * LDA + k0 + c8 * 8,
                  &As[buf][o * 512]);
      gload_lds16(B + (size_t)(brow + row) * LDB + kb + k0 + c8 * 8,
                  &Bs[buf][o * 512]);
    }
  };

  stage(0, 0);
  asm volatile("s_waitcnt vmcnt(0)" ::: "memory");
  __builtin_amdgcn_s_barrier();

  for (int t = 0; t < ksteps; ++t) {
    int buf = t & 1;
    if (t + 1 < ksteps) stage(buf ^ 1, (t + 1) * 32);
    bf16x8 af[4], bfr[4];
#pragma unroll
    for (int mt = 0; mt < 4; ++mt)
      af[mt] = *(const bf16x8*)&As[buf][(wm * 64 + mt * 16 + l15) * 32 + g * 8];
#pragma unroll
    for (int nt = 0; nt < 4; ++nt)
      bfr[nt] = *(const bf16x8*)&Bs[buf][(wn * 64 + nt * 16 + l15) * 32 + g * 8];
#pragma unroll
    for (int mt = 0; mt < 4; ++mt)
#pragma unroll
      for (int nt = 0; nt < 4; ++nt)
        acc[mt][nt] = __builtin_amdgcn_mfma_f32_16x16x32_bf16(
            af[mt], bfr[nt], acc[mt][nt], 0, 0, 0);
    asm volatile("s_waitcnt vmcnt(0)" ::: "memory");
    __builtin_amdgcn_s_barrier();
  }

#pragma unroll
  for (int mt = 0; mt < 4; ++mt) {
#pragma unroll
    for (int r = 0; r < 4; ++r) {
      int ro = wm * 64 + mt * 16 + g * 4 + r;
      int co = wn * 64 + l15;
      if constexpr (MODE == 3) {
        float* Cp = (float*)Cv + cbase + (size_t)ro * LDC + co;
#pragma unroll
        for (int nt = 0; nt < 4; ++nt) Cp[nt * 16] = acc[mt][nt][r];
      } else {
        unsigned short* Cp = (unsigned short*)Cv + cbase + (size_t)ro * LDC + co;
#pragma unroll
        for (int nt = 0; nt < 4; ++nt) Cp[nt * 16] = f2bf(acc[mt][nt][r]);
      }
    }
  }
}

// ---------------------------------------------------------------- softmax
// In-place row softmax over the causal prefix of S [8192][2048] bf16.
// Folds the 1/sqrt(d) scale (as exp2) and the 1/l normalization into P.
// Zero-pads cols q+1 .. (q/128+1)*128-1 so the PV GEMM's padded K-extent
// reads exact zeros. One wave per row, 4 rows per block.
__global__ __launch_bounds__(256) void softmax_kernel(
    unsigned short* __restrict__ S) {
  const int r = blockIdx.x * 4 + (threadIdx.x >> 6);
  const int lane = threadIdx.x & 63;
  const int q = r & 2047;
  unsigned short* row = S + (size_t)r * 2048;
  const int klen = q + 1;
  const int kmax = ((q >> 7) + 1) << 7;  // padded extent (tile boundary)

  float v[4][8];
  float m = -__builtin_inff();
#pragma unroll
  for (int it = 0; it < 4; ++it) {
    int base = (lane + it * 64) * 8;
    if (base < klen) {
      bf16x8 u = *(const bf16x8*)(row + base);
#pragma unroll
      for (int e = 0; e < 8; ++e) {
        float f = bf2f((unsigned short)u[e]) * CSCALE;
        v[it][e] = (base + e <= q) ? f : -__builtin_inff();
        m = fmaxf(m, v[it][e]);
      }
    } else {
#pragma unroll
      for (int e = 0; e < 8; ++e) v[it][e] = -__builtin_inff();
    }
  }
#pragma unroll
  for (int s = 1; s < 64; s <<= 1) m = fmaxf(m, __shfl_xor(m, s));

  float lsum = 0.f;
#pragma unroll
  for (int it = 0; it < 4; ++it)
#pragma unroll
    for (int e = 0; e < 8; ++e) {
      float p = exp2f(v[it][e] - m);
      v[it][e] = p;
      lsum += p;
    }
#pragma unroll
  for (int s = 1; s < 64; s <<= 1) lsum += __shfl_xor(lsum, s);
  float inv = 1.0f / lsum;

#pragma unroll
  for (int it = 0; it < 4; ++it) {
    int base = (lane + it * 64) * 8;
    if (base < kmax) {
      union { unsigned short u[8]; uint4 x; } o;
#pragma unroll
      for (int e = 0; e < 8; ++e) o.u[e] = f2bf(v[it][e] * inv);
      *(uint4*)(row + base) = o.x;
    }
  }
}

// ---------------------------------------------------------------- launch
extern "C" void kernel_launch(void* const* d_in, const int* in_sizes, int n_in,
                              void* d_out, int out_size, void* d_ws,
                              size_t ws_size, hipStream_t stream) {
  const float* x = (const float*)d_in[0];
  const float* Wq = (const float*)d_in[1];
  const float* Wk = (const float*)d_in[2];
  const float* Wv = (const float*)d_in[3];
  unsigned short* ws = (unsigned short*)d_ws;
  // ws layout (bf16 elements):
  //   xb   @ 0    : 8M  (16 MB)   x as bf16 [8192][1024]
  //   Wqk  @ 8M   : 2M  ( 4 MB)   [Wq;Wk] bf16 [2048][1024]
  //   Wvb  @ 10M  : 1M  ( 2 MB)   Wv bf16 [1024][1024]
  //   QKb  @ 11M  : 16M (32 MB)   [Q|K] bf16 [8192][2048]
  //   Vtb  @ 27M  : 8M  (16 MB)   V^T bf16 [1024][8192]
  //   S/P  @ 35M  : 16M (32 MB)   scores -> probs bf16 [8192][2048]
  // total 102 MB
  unsigned short* xb = ws;
  unsigned short* Wqk = ws + (size_t)(8u << 20);
  unsigned short* Wvb = ws + (size_t)(10u << 20);
  unsigned short* QKb = ws + (size_t)(11u << 20);
  unsigned short* Vtb = ws + (size_t)(27u << 20);
  unsigned short* Sb = ws + (size_t)(35u << 20);

  cvt_kernel<<<4096, 256, 0, stream>>>(x, xb, 1048576);
  cvt_kernel<<<512, 256, 0, stream>>>(Wq, Wqk, 131072);
  cvt_kernel<<<512, 256, 0, stream>>>(Wk, Wqk + (size_t)(1u << 20), 131072);
  cvt_kernel<<<512, 256, 0, stream>>>(Wv, Wvb, 131072);
  // QK = xb @ [Wq;Wk]^T : [8192 x 2048]
  gemm_k<0><<<dim3(64, 16), 256, 0, stream>>>(xb, Wqk, QKb);
  // Vt = Wv @ xb^T : [1024 x 8192]
  gemm_k<1><<<dim3(8, 64), 256, 0, stream>>>(Wvb, xb, Vtb);
  // S = Q @ K^T (causal lower-triangle tiles), batched over b
  gemm_k<2><<<dim3(16, 16, 4), 256, 0, stream>>>(QKb, QKb + 1024, Sb);
  // P = softmax(S * scale) / l, zero-padded to tile boundary
  softmax_kernel<<<2048, 256, 0, stream>>>(Sb);
  // Out = P @ V : [8192 x 1024] fp32
  gemm_k<3><<<dim3(64, 8), 256, 0, stream>>>(Sb, Vtb, (float*)d_out);
}

// Round 3
// 259.355 us; speedup vs baseline: 1.7489x; 1.1056x over previous
//
#include <hip/hip_runtime.h>
#include <cstdint>
#include <cstddef>

typedef __attribute__((ext_vector_type(8))) short bf16x8;
typedef __attribute__((ext_vector_type(4))) float f32x4;

#define CSCALE 0.045084220027780106f /* log2(e) / sqrt(1024) */

__device__ __forceinline__ void gload_lds16(const void* g, void* l) {
  __builtin_amdgcn_global_load_lds(
      (const __attribute__((address_space(1))) unsigned int*)g,
      (__attribute__((address_space(3))) unsigned int*)l, 16, 0, 0);
}

__device__ __forceinline__ unsigned short f2bf(float f) {
  unsigned int u = __float_as_uint(f);
  return (unsigned short)((u + 0x7FFFu + ((u >> 16) & 1u)) >> 16);
}

__device__ __forceinline__ float bf2f(unsigned short u) {
  return __uint_as_float((unsigned int)u << 16);
}

// ---------------------------------------------------------------- convert
__global__ void cvt_kernel(const float* __restrict__ in,
                           unsigned short* __restrict__ out, int n8) {
  int i = blockIdx.x * blockDim.x + threadIdx.x;
  if (i >= n8) return;
  const float4* p = (const float4*)in + (size_t)i * 2;
  float4 a = p[0], b = p[1];
  float vals[8] = {a.x, a.y, a.z, a.w, b.x, b.y, b.z, b.w};
  union { unsigned short u[8]; uint4 v; } r;
#pragma unroll
  for (int j = 0; j < 8; ++j) r.u[j] = f2bf(vals[j]);
  ((uint4*)out)[i] = r.v;
}

// all three weights in one launch (512 blocks each)
__global__ void cvt3_kernel(const float* __restrict__ a,
                            const float* __restrict__ b,
                            const float* __restrict__ c,
                            unsigned short* __restrict__ oa,
                            unsigned short* __restrict__ ob,
                            unsigned short* __restrict__ oc) {
  int bid = blockIdx.x;
  const float* src;
  unsigned short* dst;
  int base;
  if (bid < 512) { src = a; dst = oa; base = bid; }
  else if (bid < 1024) { src = b; dst = ob; base = bid - 512; }
  else { src = c; dst = oc; base = bid - 1024; }
  int i = base * 256 + threadIdx.x;
  const float4* p = (const float4*)src + (size_t)i * 2;
  float4 x = p[0], y = p[1];
  float vals[8] = {x.x, x.y, x.z, x.w, y.x, y.y, y.z, y.w};
  union { unsigned short u[8]; uint4 v; } r;
#pragma unroll
  for (int j = 0; j < 8; ++j) r.u[j] = f2bf(vals[j]);
  ((uint4*)dst)[i] = r.v;
}

// ---------------------------------------------------------------- GEMM
// 8-phase-class schedule: BM=256, BN=128, BK=64, 8 waves (2Mx4N), 512 thr.
// Triple-buffered LDS (3 x (32K A + 16K B) = 144 KB). Iteration T computes
// tile T (buf T%3) in 2 phases of {12 ds_read_b128 | 3 global_load_lds ->
// barrier -> lgkmcnt(0) -> setprio(1) 16 MFMA setprio(0) -> barrier},
// stages tile T+2 into buf (T+2)%3 (freed at end of T-1), and ends with
// s_waitcnt vmcnt(6) (= tile T+2's 6 loads outstanding) so tile T+1 is
// guaranteed landed. Never drains vmcnt to 0 until the tail (T3+T4).
// LDS XOR-swizzle byte ^= ((row&7)<<4), applied on BOTH sides: pre-swizzled
// global source (linear gload_lds dest) + swizzled ds_read (T2, rule #21).
//
// C = A * B^T over the K axis.
// MODE 0: proj  A=xb[8192][1024]  B=Wqk[2048][1024]  C=QK bf16 [8192][2048]
// MODE 1: Vt    A=Wv[1024][1024]  B=xb[8192][1024]   C=Vt bf16 [1024][8192]
// MODE 2: S     A=QK(Q)           B=QK+1024(K)       C=S  bf16 [8192][2048]
//               grid(8,16,4): 256-row q-tiles x 128-col k-tiles, jt<=2qt+1
// MODE 3: PV    A=P[8192][2048]   B=Vt[1024][8192]   C=Out f32 [8192][1024]
//               nt=(qt+1)*4, longest-first, B col offset b*2048
template <int MODE>
__device__ __forceinline__ void gemm8_body(const unsigned short* __restrict__ A,
                                           const unsigned short* __restrict__ B,
                                           void* __restrict__ Cv) {
  constexpr int LDA = (MODE <= 1) ? 1024 : 2048;
  constexpr int LDB = (MODE <= 1) ? 1024 : (MODE == 2 ? 2048 : 8192);
  constexpr int LDC =
      (MODE == 0) ? 2048 : (MODE == 1 ? 8192 : (MODE == 2 ? 2048 : 1024));

  int arow, brow, nt = 16, kb = 0;
  size_t cbase;
  if constexpr (MODE == 0 || MODE == 1) {
    arow = blockIdx.x * 256;
    brow = blockIdx.y * 128;
    cbase = (size_t)arow * LDC + blockIdx.y * 128;
  } else if constexpr (MODE == 2) {
    int qt = blockIdx.x, jt = blockIdx.y, b = blockIdx.z;
    if (jt > 2 * qt + 1) return;  // causal: above-diagonal tiles never read
    arow = b * 2048 + qt * 256;
    brow = b * 2048 + jt * 128;
    cbase = (size_t)arow * LDC + jt * 128;
  } else {
    int bm = blockIdx.x;
    int b = bm >> 3, qt = 7 - (bm & 7);  // longest K-extent first
    arow = b * 2048 + qt * 256;
    brow = blockIdx.y * 128;
    kb = b * 2048;
    nt = (qt + 1) * 4;
    cbase = (size_t)arow * LDC + blockIdx.y * 128;
  }

  __shared__ unsigned short As[3][256 * 64];  // 96 KB
  __shared__ unsigned short Bs[3][128 * 64];  // 48 KB

  const int tid = threadIdx.x;  // 0..511
  const int lane = tid & 63;
  const int l15 = lane & 15, g = lane >> 4;
  const int w = tid >> 6;
  const int wm = w >> 2, wn = w & 3;  // 2M x 4N; per-wave out 128 x 32

  f32x4 acc[8][2] = {};

  // op 0..3 = A half-tiles (8KB each), op 4..5 = B (one gload_lds16/thread)
  auto stage_op = [&](int buf, int t, int op) {
    int k0 = t * 64;
    if (op < 4) {
      int chunk = op * 512 + tid;  // 16B chunks, 0..2047
      int row = chunk >> 3, c8 = chunk & 7;
      int ce = (c8 * 16) ^ ((row & 7) << 4);  // pre-swizzled source column
      gload_lds16(A + (size_t)(arow + row) * LDA + k0 + (ce >> 1),
                  &As[buf][(op * 512 + (tid & ~63)) * 8]);
    } else {
      int chunk = (op - 4) * 512 + tid;  // 0..1023
      int row = chunk >> 3, c8 = chunk & 7;
      int ce = (c8 * 16) ^ ((row & 7) << 4);
      gload_lds16(B + (size_t)(brow + row) * LDB + kb + k0 + (ce >> 1),
                  &Bs[buf][((op - 4) * 512 + (tid & ~63)) * 8]);
    }
  };

  auto lda_frag = [&](int buf, int mt, int kk) -> bf16x8 {
    int row = wm * 128 + mt * 16 + l15;
    int byte = (row * 128 + kk * 64 + g * 16) ^ ((l15 & 7) << 4);
    return *(const bf16x8*)((const char*)&As[buf][0] + byte);
  };
  auto ldb_frag = [&](int buf, int n2, int kk) -> bf16x8 {
    int row = wn * 32 + n2 * 16 + l15;
    int byte = (row * 128 + kk * 64 + g * 16) ^ ((l15 & 7) << 4);
    return *(const bf16x8*)((const char*)&Bs[buf][0] + byte);
  };

  // prologue: tiles 0 and 1; wait for tile 0 (6 loads of tile 1 in flight)
#pragma unroll
  for (int op = 0; op < 6; ++op) stage_op(0, 0, op);
#pragma unroll
  for (int op = 0; op < 6; ++op) stage_op(1, 1, op);
  asm volatile("s_waitcnt vmcnt(6)" ::: "memory");
  __builtin_amdgcn_s_barrier();

  for (int t = 0; t < nt; ++t) {
    int buf = t % 3;
    int sbuf = (t + 2) % 3;
    bool do_stage = (t + 2) < nt;
#pragma unroll
    for (int ph = 0; ph < 2; ++ph) {
      bf16x8 af[4][2], bv[2][2];
#pragma unroll
      for (int mt = 0; mt < 4; ++mt)
#pragma unroll
        for (int kk = 0; kk < 2; ++kk)
          af[mt][kk] = lda_frag(buf, ph * 4 + mt, kk);
#pragma unroll
      for (int n2 = 0; n2 < 2; ++n2)
#pragma unroll
        for (int kk = 0; kk < 2; ++kk) bv[n2][kk] = ldb_frag(buf, n2, kk);
      if (do_stage) {
        if (ph == 0) {
          stage_op(sbuf, t + 2, 0);
          stage_op(sbuf, t + 2, 1);
          stage_op(sbuf, t + 2, 4);
        } else {
          stage_op(sbuf, t + 2, 2);
          stage_op(sbuf, t + 2, 3);
          stage_op(sbuf, t + 2, 5);
        }
      }
      __builtin_amdgcn_s_barrier();
      asm volatile("s_waitcnt lgkmcnt(0)" ::: "memory");
      __builtin_amdgcn_sched_barrier(0);
      __builtin_amdgcn_s_setprio(1);
#pragma unroll
      for (int mt = 0; mt < 4; ++mt)
#pragma unroll
        for (int n2 = 0; n2 < 2; ++n2)
#pragma unroll
          for (int kk = 0; kk < 2; ++kk)
            acc[ph * 4 + mt][n2] = __builtin_amdgcn_mfma_f32_16x16x32_bf16(
                af[mt][kk], bv[n2][kk], acc[ph * 4 + mt][n2], 0, 0, 0);
      __builtin_amdgcn_s_setprio(0);
      __builtin_amdgcn_s_barrier();
    }
    if (do_stage) {
      asm volatile("s_waitcnt vmcnt(6)" ::: "memory");  // tile t+1 landed
    } else if (t + 1 < nt) {
      asm volatile("s_waitcnt vmcnt(0)" ::: "memory");  // tail drain
    }
  }

#pragma unroll
  for (int mt = 0; mt < 8; ++mt) {
#pragma unroll
    for (int r = 0; r < 4; ++r) {
      int ro = wm * 128 + mt * 16 + g * 4 + r;
      int co = wn * 32 + l15;
      if constexpr (MODE == 3) {
        float* Cp = (float*)Cv + cbase + (size_t)ro * LDC + co;
        Cp[0] = acc[mt][0][r];
        Cp[16] = acc[mt][1][r];
      } else {
        unsigned short* Cp =
            (unsigned short*)Cv + cbase + (size_t)ro * LDC + co;
        Cp[0] = f2bf(acc[mt][0][r]);
        Cp[16] = f2bf(acc[mt][1][r]);
      }
    }
  }
}

__global__ __launch_bounds__(512) void gemm_proj(
    const unsigned short* __restrict__ A, const unsigned short* __restrict__ B,
    void* __restrict__ C) { gemm8_body<0>(A, B, C); }
__global__ __launch_bounds__(512) void gemm_vt(
    const unsigned short* __restrict__ A, const unsigned short* __restrict__ B,
    void* __restrict__ C) { gemm8_body<1>(A, B, C); }
__global__ __launch_bounds__(512) void gemm_s(
    const unsigned short* __restrict__ A, const unsigned short* __restrict__ B,
    void* __restrict__ C) { gemm8_body<2>(A, B, C); }
__global__ __launch_bounds__(512) void gemm_pv(
    const unsigned short* __restrict__ A, const unsigned short* __restrict__ B,
    void* __restrict__ C) { gemm8_body<3>(A, B, C); }

// ---------------------------------------------------------------- softmax
// In-place row softmax over the causal prefix of S [8192][2048] bf16.
// Folds the 1/sqrt(d) scale (as exp2) and the 1/l normalization into P.
// Zero-pads cols q+1 .. kmax-1 where kmax = 256-boundary, so the PV GEMM's
// padded K-extent (multiples of 256 per 256-row q-tile) reads exact zeros.
__global__ __launch_bounds__(256) void softmax_kernel(
    unsigned short* __restrict__ S) {
  const int r = blockIdx.x * 4 + (threadIdx.x >> 6);
  const int lane = threadIdx.x & 63;
  const int q = r & 2047;
  unsigned short* row = S + (size_t)r * 2048;
  const int klen = q + 1;
  const int kmax = ((q >> 8) + 1) << 8;  // padded extent (256-tile boundary)

  float v[4][8];
  float m = -__builtin_inff();
#pragma unroll
  for (int it = 0; it < 4; ++it) {
    int base = (lane + it * 64) * 8;
    if (base < klen) {
      bf16x8 u = *(const bf16x8*)(row + base);
#pragma unroll
      for (int e = 0; e < 8; ++e) {
        float f = bf2f((unsigned short)u[e]) * CSCALE;
        v[it][e] = (base + e <= q) ? f : -__builtin_inff();
        m = fmaxf(m, v[it][e]);
      }
    } else {
#pragma unroll
      for (int e = 0; e < 8; ++e) v[it][e] = -__builtin_inff();
    }
  }
#pragma unroll
  for (int s = 1; s < 64; s <<= 1) m = fmaxf(m, __shfl_xor(m, s));

  float lsum = 0.f;
#pragma unroll
  for (int it = 0; it < 4; ++it)
#pragma unroll
    for (int e = 0; e < 8; ++e) {
      float p = exp2f(v[it][e] - m);
      v[it][e] = p;
      lsum += p;
    }
#pragma unroll
  for (int s = 1; s < 64; s <<= 1) lsum += __shfl_xor(lsum, s);
  float inv = 1.0f / lsum;

#pragma unroll
  for (int it = 0; it < 4; ++it) {
    int base = (lane + it * 64) * 8;
    if (base < kmax) {
      union { unsigned short u[8]; uint4 x; } o;
#pragma unroll
      for (int e = 0; e < 8; ++e) o.u[e] = f2bf(v[it][e] * inv);
      *(uint4*)(row + base) = o.x;
    }
  }
}

// ---------------------------------------------------------------- launch
extern "C" void kernel_launch(void* const* d_in, const int* in_sizes, int n_in,
                              void* d_out, int out_size, void* d_ws,
                              size_t ws_size, hipStream_t stream) {
  const float* x = (const float*)d_in[0];
  const float* Wq = (const float*)d_in[1];
  const float* Wk = (const float*)d_in[2];
  const float* Wv = (const float*)d_in[3];
  unsigned short* ws = (unsigned short*)d_ws;
  // ws layout (bf16 elements):
  //   xb   @ 0    : 8M  (16 MB)   x as bf16 [8192][1024]
  //   Wqk  @ 8M   : 2M  ( 4 MB)   [Wq;Wk] bf16 [2048][1024]
  //   Wvb  @ 10M  : 1M  ( 2 MB)   Wv bf16 [1024][1024]
  //   QKb  @ 11M  : 16M (32 MB)   [Q|K] bf16 [8192][2048]
  //   Vtb  @ 27M  : 8M  (16 MB)   V^T bf16 [1024][8192]
  //   S/P  @ 35M  : 16M (32 MB)   scores -> probs bf16 [8192][2048]
  unsigned short* xb = ws;
  unsigned short* Wqk = ws + (size_t)(8u << 20);
  unsigned short* Wvb = ws + (size_t)(10u << 20);
  unsigned short* QKb = ws + (size_t)(11u << 20);
  unsigned short* Vtb = ws + (size_t)(27u << 20);
  unsigned short* Sb = ws + (size_t)(35u << 20);

  cvt_kernel<<<4096, 256, 0, stream>>>(x, xb, 1048576);
  cvt3_kernel<<<1536, 256, 0, stream>>>(Wq, Wk, Wv, Wqk,
                                        Wqk + (size_t)(1u << 20), Wvb);
  // QK = xb @ [Wq;Wk]^T : [8192 x 2048]
  gemm_proj<<<dim3(32, 16), 512, 0, stream>>>(xb, Wqk, QKb);
  // Vt = Wv @ xb^T : [1024 x 8192]
  gemm_vt<<<dim3(4, 64), 512, 0, stream>>>(Wvb, xb, Vtb);
  // S = Q @ K^T (causal tiles: 256-row x 128-col, jt <= 2qt+1), batched
  gemm_s<<<dim3(8, 16, 4), 512, 0, stream>>>(QKb, QKb + 1024, Sb);
  // P = softmax(S * scale) / l, zero-padded to 256-tile boundary
  softmax_kernel<<<2048, 256, 0, stream>>>(Sb);
  // Out = P @ V : [8192 x 1024] fp32
  gemm_pv<<<dim3(32, 8), 512, 0, stream>>>(Sb, Vtb, (float*)d_out);
}

// Round 4
// 251.275 us; speedup vs baseline: 1.8052x; 1.0322x over previous
//
#include <hip/hip_runtime.h>
#include <cstdint>
#include <cstddef>

typedef __attribute__((ext_vector_type(8))) short bf16x8;
typedef __attribute__((ext_vector_type(4))) float f32x4;

#define CSCALE 0.045084220027780106f /* log2(e) / sqrt(1024) */

__device__ __forceinline__ void gload_lds16(const void* g, void* l) {
  __builtin_amdgcn_global_load_lds(
      (const __attribute__((address_space(1))) unsigned int*)g,
      (__attribute__((address_space(3))) unsigned int*)l, 16, 0, 0);
}

__device__ __forceinline__ unsigned short f2bf(float f) {
  unsigned int u = __float_as_uint(f);
  return (unsigned short)((u + 0x7FFFu + ((u >> 16) & 1u)) >> 16);
}

__device__ __forceinline__ float bf2f(unsigned short u) {
  return __uint_as_float((unsigned int)u << 16);
}

// ---------------------------------------------------------------- convert
__global__ void cvt_kernel(const float* __restrict__ in,
                           unsigned short* __restrict__ out, int n8) {
  int i = blockIdx.x * blockDim.x + threadIdx.x;
  if (i >= n8) return;
  const float4* p = (const float4*)in + (size_t)i * 2;
  float4 a = p[0], b = p[1];
  float vals[8] = {a.x, a.y, a.z, a.w, b.x, b.y, b.z, b.w};
  union { unsigned short u[8]; uint4 v; } r;
#pragma unroll
  for (int j = 0; j < 8; ++j) r.u[j] = f2bf(vals[j]);
  ((uint4*)out)[i] = r.v;
}

__global__ void cvt3_kernel(const float* __restrict__ a,
                            const float* __restrict__ b,
                            const float* __restrict__ c,
                            unsigned short* __restrict__ oa,
                            unsigned short* __restrict__ ob,
                            unsigned short* __restrict__ oc) {
  int bid = blockIdx.x;
  const float* src;
  unsigned short* dst;
  int base;
  if (bid < 512) { src = a; dst = oa; base = bid; }
  else if (bid < 1024) { src = b; dst = ob; base = bid - 512; }
  else { src = c; dst = oc; base = bid - 1024; }
  int i = base * 256 + threadIdx.x;
  const float4* p = (const float4*)src + (size_t)i * 2;
  float4 x = p[0], y = p[1];
  float vals[8] = {x.x, x.y, x.z, x.w, y.x, y.y, y.z, y.w};
  union { unsigned short u[8]; uint4 v; } r;
#pragma unroll
  for (int j = 0; j < 8; ++j) r.u[j] = f2bf(vals[j]);
  ((uint4*)dst)[i] = r.v;
}

// ---------------------------------------------------------------- GEMM
// 128x128 tile, 4 waves (2x2 of 64x64), BK=32, ring of 4 LDS K-tile slots
// (64 KB -> 2 blocks/CU). Per K-tile j: 2 phases (n-halves), each
// {ds_read frags | stage one 8KB part of tile j+3 (2 gload_lds) -> barrier
//  -> lgkmcnt(0)+sched_barrier -> setprio(1) 8 MFMA setprio(0) -> barrier};
// one counted s_waitcnt vmcnt(4) per K-tile (never drains until tail).
// Ledger: tile j's parts staged during tile j-3; vmcnt(4) at end of j-1
// leaves only tile j+2's 4 loads outstanding => tile j landed; cross-wave
// completeness via each wave's own vmcnt followed by shared barriers.
// LDS slot layout (64-B rows): row placement swaps bits 0<->2, 16B-granule
// column XOR (g ^ row&3) => exactly 2-way banks on ds_read_b128 (free).
// Staging pre-swizzles the GLOBAL source; gload_lds dest stays linear.
//
// C = A * B^T over the K axis.
// MODE 0: proj  A=xb[8192][1024]  B=Wqk[2048][1024]  C=QK bf16 [8192][2048]
// MODE 1: Vt    A=Wv[1024][1024]  B=xb[8192][1024]   C=Vt bf16 [1024][8192]
// MODE 2: S     A=QK(Q part)      B=QK+1024 (K part) C=S  bf16 [8192][2048]
//               grid(16,16,4), causal: jt<=qt only
// MODE 3: PV    A=P[8192][2048]   B=Vt[1024][8192]   C=Out f32 [8192][1024]
//               NT=(qt+1)*4 K-tiles, longest-first; B col offset b*2048
template <int MODE>
__device__ __forceinline__ void gemm_body(const unsigned short* __restrict__ A,
                                          const unsigned short* __restrict__ B,
                                          void* __restrict__ Cv) {
  constexpr int LDA = (MODE <= 1) ? 1024 : 2048;
  constexpr int LDB = (MODE <= 1) ? 1024 : (MODE == 2 ? 2048 : 8192);
  constexpr int LDC =
      (MODE == 0) ? 2048 : (MODE == 1 ? 8192 : (MODE == 2 ? 2048 : 1024));

  int arow, brow, NT = 32, kb = 0;
  size_t cbase;
  if constexpr (MODE == 0 || MODE == 1) {
    arow = blockIdx.x * 128;
    brow = blockIdx.y * 128;
    cbase = (size_t)arow * LDC + blockIdx.y * 128;
  } else if constexpr (MODE == 2) {
    int qt = blockIdx.x, jt = blockIdx.y, b = blockIdx.z;
    if (jt > qt) return;  // causal: these S-tiles are never read
    arow = b * 2048 + qt * 128;
    brow = b * 2048 + jt * 128;
    cbase = (size_t)arow * LDC + jt * 128;
  } else {
    int b = blockIdx.x >> 4, qt = 15 - (blockIdx.x & 15);  // longest first
    arow = b * 2048 + qt * 128;
    brow = blockIdx.y * 128;
    kb = b * 2048;
    NT = (qt + 1) * 4;
    cbase = (size_t)arow * LDC + blockIdx.y * 128;
  }

  __shared__ char lds[4][16384];  // slot: A 8KB @0, B 8KB @8192; total 64 KB
  const int tid = threadIdx.x, lane = tid & 63;
  const int l15 = lane & 15, g = lane >> 4;
  const int w = tid >> 6, wm = w >> 1, wn = w & 1;  // 2x2 waves, 64x64 each

  f32x4 acc[4][4] = {};

  // stage one 8 KB part (A or B) of K-tile jt into slot; 2 gload_lds/thread.
  // LDS granule q (16B): prow=q>>2 (permuted row), granule c''=q&3.
  // Source row = swap02(prow), source k-granule = c'' ^ (row&3).
  auto stageA = [&](int slot, int jt) {
#pragma unroll
    for (int h = 0; h < 2; ++h) {
      int q = h * 256 + tid;
      int prow = q >> 2;
      int row = (prow & ~5) | ((prow & 1) << 2) | ((prow >> 2) & 1);
      int c = (q & 3) ^ (row & 3);
      gload_lds16(A + (size_t)(arow + row) * LDA + jt * 32 + c * 8,
                  &lds[slot][(q & ~63) * 16]);
    }
  };
  auto stageB = [&](int slot, int jt) {
#pragma unroll
    for (int h = 0; h < 2; ++h) {
      int q = h * 256 + tid;
      int prow = q >> 2;
      int row = (prow & ~5) | ((prow & 1) << 2) | ((prow >> 2) & 1);
      int c = (q & 3) ^ (row & 3);
      gload_lds16(B + (size_t)(brow + row) * LDB + kb + jt * 32 + c * 8,
                  &lds[slot][8192 + (q & ~63) * 16]);
    }
  };
  // frag read: logical (row = r16*16+l15, k-granule g) -> swizzled LDS addr
  auto ldf = [&](int slot, int off, int r16) -> bf16x8 {
    int row = r16 * 16 + l15;
    int prow = (row & ~5) | ((row & 1) << 2) | ((row >> 2) & 1);
    return *(const bf16x8*)&lds[slot]
        [off + prow * 64 + (((g ^ row) & 3) << 4)];
  };

  // prologue: stage tiles 0,1,2 (12 loads); confirm tile 0 (8 left in flight)
  stageA(0, 0); stageB(0, 0);
  stageA(1, 1); stageB(1, 1);
  stageA(2, 2); stageB(2, 2);
  asm volatile("s_waitcnt vmcnt(8)" ::: "memory");
  __builtin_amdgcn_s_barrier();

  for (int j = 0; j < NT; ++j) {
    int slot = j & 3, ss = (j + 3) & 3;
    bool st = (j + 3) < NT;
    // ---- phase A: n-half 0 ----
    bf16x8 af[4];
#pragma unroll
    for (int mt = 0; mt < 4; ++mt) af[mt] = ldf(slot, 0, wm * 4 + mt);
    bf16x8 bv0 = ldf(slot, 8192, wn * 4 + 0);
    bf16x8 bv1 = ldf(slot, 8192, wn * 4 + 1);
    if (st) stageA(ss, j + 3);
    __builtin_amdgcn_s_barrier();
    asm volatile("s_waitcnt lgkmcnt(0)" ::: "memory");
    __builtin_amdgcn_sched_barrier(0);
    __builtin_amdgcn_s_setprio(1);
#pragma unroll
    for (int mt = 0; mt < 4; ++mt) {
      acc[mt][0] =
          __builtin_amdgcn_mfma_f32_16x16x32_bf16(af[mt], bv0, acc[mt][0], 0, 0, 0);
      acc[mt][1] =
          __builtin_amdgcn_mfma_f32_16x16x32_bf16(af[mt], bv1, acc[mt][1], 0, 0, 0);
    }
    __builtin_amdgcn_s_setprio(0);
    __builtin_amdgcn_s_barrier();
    // ---- phase B: n-half 1 (reuse af) ----
    bf16x8 bv2 = ldf(slot, 8192, wn * 4 + 2);
    bf16x8 bv3 = ldf(slot, 8192, wn * 4 + 3);
    if (st) stageB(ss, j + 3);
    __builtin_amdgcn_s_barrier();
    asm volatile("s_waitcnt lgkmcnt(0)" ::: "memory");
    __builtin_amdgcn_sched_barrier(0);
    __builtin_amdgcn_s_setprio(1);
#pragma unroll
    for (int mt = 0; mt < 4; ++mt) {
      acc[mt][2] =
          __builtin_amdgcn_mfma_f32_16x16x32_bf16(af[mt], bv2, acc[mt][2], 0, 0, 0);
      acc[mt][3] =
          __builtin_amdgcn_mfma_f32_16x16x32_bf16(af[mt], bv3, acc[mt][3], 0, 0, 0);
    }
    __builtin_amdgcn_s_setprio(0);
    __builtin_amdgcn_s_barrier();
    if (st) {
      asm volatile("s_waitcnt vmcnt(4)" ::: "memory");  // tile j+2 landed
    } else {
      asm volatile("s_waitcnt vmcnt(0)" ::: "memory");  // tail drain
    }
  }

#pragma unroll
  for (int mt = 0; mt < 4; ++mt) {
#pragma unroll
    for (int r = 0; r < 4; ++r) {
      int ro = wm * 64 + mt * 16 + g * 4 + r;
      int co = wn * 64 + l15;
      if constexpr (MODE == 3) {
        float* Cp = (float*)Cv + cbase + (size_t)ro * LDC + co;
#pragma unroll
        for (int n2 = 0; n2 < 4; ++n2) Cp[n2 * 16] = acc[mt][n2][r];
      } else {
        unsigned short* Cp = (unsigned short*)Cv + cbase + (size_t)ro * LDC + co;
#pragma unroll
        for (int n2 = 0; n2 < 4; ++n2) Cp[n2 * 16] = f2bf(acc[mt][n2][r]);
      }
    }
  }
}

__global__ __launch_bounds__(256, 2) void gemm_proj(
    const unsigned short* __restrict__ A, const unsigned short* __restrict__ B,
    void* __restrict__ C) { gemm_body<0>(A, B, C); }
__global__ __launch_bounds__(256, 2) void gemm_vt(
    const unsigned short* __restrict__ A, const unsigned short* __restrict__ B,
    void* __restrict__ C) { gemm_body<1>(A, B, C); }
__global__ __launch_bounds__(256, 2) void gemm_s(
    const unsigned short* __restrict__ A, const unsigned short* __restrict__ B,
    void* __restrict__ C) { gemm_body<2>(A, B, C); }
__global__ __launch_bounds__(256, 2) void gemm_pv(
    const unsigned short* __restrict__ A, const unsigned short* __restrict__ B,
    void* __restrict__ C) { gemm_body<3>(A, B, C); }

// ---------------------------------------------------------------- softmax
// In-place row softmax over the causal prefix of S [8192][2048] bf16.
// Folds the 1/sqrt(d) scale (as exp2) and the 1/l normalization into P.
// Zero-pads cols q+1 .. kmax-1, kmax = 128-tile boundary, so the PV GEMM's
// padded K-extent reads exact zeros.
__global__ __launch_bounds__(256) void softmax_kernel(
    unsigned short* __restrict__ S) {
  const int r = blockIdx.x * 4 + (threadIdx.x >> 6);
  const int lane = threadIdx.x & 63;
  const int q = r & 2047;
  unsigned short* row = S + (size_t)r * 2048;
  const int klen = q + 1;
  const int kmax = ((q >> 7) + 1) << 7;  // padded extent (128-tile boundary)

  float v[4][8];
  float m = -__builtin_inff();
#pragma unroll
  for (int it = 0; it < 4; ++it) {
    int base = (lane + it * 64) * 8;
    if (base < klen) {
      bf16x8 u = *(const bf16x8*)(row + base);
#pragma unroll
      for (int e = 0; e < 8; ++e) {
        float f = bf2f((unsigned short)u[e]) * CSCALE;
        v[it][e] = (base + e <= q) ? f : -__builtin_inff();
        m = fmaxf(m, v[it][e]);
      }
    } else {
#pragma unroll
      for (int e = 0; e < 8; ++e) v[it][e] = -__builtin_inff();
    }
  }
#pragma unroll
  for (int s = 1; s < 64; s <<= 1) m = fmaxf(m, __shfl_xor(m, s));

  float lsum = 0.f;
#pragma unroll
  for (int it = 0; it < 4; ++it)
#pragma unroll
    for (int e = 0; e < 8; ++e) {
      float p = exp2f(v[it][e] - m);
      v[it][e] = p;
      lsum += p;
    }
#pragma unroll
  for (int s = 1; s < 64; s <<= 1) lsum += __shfl_xor(lsum, s);
  float inv = 1.0f / lsum;

#pragma unroll
  for (int it = 0; it < 4; ++it) {
    int base = (lane + it * 64) * 8;
    if (base < kmax) {
      union { unsigned short u[8]; uint4 x; } o;
#pragma unroll
      for (int e = 0; e < 8; ++e) o.u[e] = f2bf(v[it][e] * inv);
      *(uint4*)(row + base) = o.x;
    }
  }
}

// ---------------------------------------------------------------- launch
extern "C" void kernel_launch(void* const* d_in, const int* in_sizes, int n_in,
                              void* d_out, int out_size, void* d_ws,
                              size_t ws_size, hipStream_t stream) {
  const float* x = (const float*)d_in[0];
  const float* Wq = (const float*)d_in[1];
  const float* Wk = (const float*)d_in[2];
  const float* Wv = (const float*)d_in[3];
  unsigned short* ws = (unsigned short*)d_ws;
  // ws layout (bf16 elements):
  //   xb   @ 0    : 8M  (16 MB)   x as bf16 [8192][1024]
  //   Wqk  @ 8M   : 2M  ( 4 MB)   [Wq;Wk] bf16 [2048][1024]
  //   Wvb  @ 10M  : 1M  ( 2 MB)   Wv bf16 [1024][1024]
  //   QKb  @ 11M  : 16M (32 MB)   [Q|K] bf16 [8192][2048]
  //   Vtb  @ 27M  : 8M  (16 MB)   V^T bf16 [1024][8192]
  //   S/P  @ 35M  : 16M (32 MB)   scores -> probs bf16 [8192][2048]
  unsigned short* xb = ws;
  unsigned short* Wqk = ws + (size_t)(8u << 20);
  unsigned short* Wvb = ws + (size_t)(10u << 20);
  unsigned short* QKb = ws + (size_t)(11u << 20);
  unsigned short* Vtb = ws + (size_t)(27u << 20);
  unsigned short* Sb = ws + (size_t)(35u << 20);

  cvt_kernel<<<4096, 256, 0, stream>>>(x, xb, 1048576);
  cvt3_kernel<<<1536, 256, 0, stream>>>(Wq, Wk, Wv, Wqk,
                                        Wqk + (size_t)(1u << 20), Wvb);
  // QK = xb @ [Wq;Wk]^T : [8192 x 2048]
  gemm_proj<<<dim3(64, 16), 256, 0, stream>>>(xb, Wqk, QKb);
  // Vt = Wv @ xb^T : [1024 x 8192]
  gemm_vt<<<dim3(8, 64), 256, 0, stream>>>(Wvb, xb, Vtb);
  // S = Q @ K^T (causal 128x128 tiles, jt <= qt), batched over b
  gemm_s<<<dim3(16, 16, 4), 256, 0, stream>>>(QKb, QKb + 1024, Sb);
  // P = softmax(S * scale) / l, zero-padded to 128-tile boundary
  softmax_kernel<<<2048, 256, 0, stream>>>(Sb);
  // Out = P @ V : [8192 x 1024] fp32
  gemm_pv<<<dim3(64, 8), 256, 0, stream>>>(Sb, Vtb, (float*)d_out);
}

// Round 5
// 249.132 us; speedup vs baseline: 1.8207x; 1.0086x over previous
//
#include <hip/hip_runtime.h>
#include <cstdint>
#include <cstddef>
#include <cmath>

typedef __attribute__((ext_vector_type(8))) short bf16x8;
typedef __attribute__((ext_vector_type(4))) float f32x4;

#define CSCALE 0.045084220027780106f /* log2(e) / sqrt(1024) */

__device__ __forceinline__ void gload_lds16(const void* g, void* l) {
  __builtin_amdgcn_global_load_lds(
      (const __attribute__((address_space(1))) unsigned int*)g,
      (__attribute__((address_space(3))) unsigned int*)l, 16, 0, 0);
}

__device__ __forceinline__ unsigned short f2bf(float f) {
  unsigned int u = __float_as_uint(f);
  return (unsigned short)((u + 0x7FFFu + ((u >> 16) & 1u)) >> 16);
}

__device__ __forceinline__ float bf2f(unsigned short u) {
  return __uint_as_float((unsigned int)u << 16);
}

// ---------------------------------------------------------------- convert
__global__ void cvt_kernel(const float* __restrict__ in,
                           unsigned short* __restrict__ out, int n8) {
  int i = blockIdx.x * blockDim.x + threadIdx.x;
  if (i >= n8) return;
  const float4* p = (const float4*)in + (size_t)i * 2;
  float4 a = p[0], b = p[1];
  float vals[8] = {a.x, a.y, a.z, a.w, b.x, b.y, b.z, b.w};
  union { unsigned short u[8]; uint4 v; } r;
#pragma unroll
  for (int j = 0; j < 8; ++j) r.u[j] = f2bf(vals[j]);
  ((uint4*)out)[i] = r.v;
}

__global__ void cvt3_kernel(const float* __restrict__ a,
                            const float* __restrict__ b,
                            const float* __restrict__ c,
                            unsigned short* __restrict__ oa,
                            unsigned short* __restrict__ ob,
                            unsigned short* __restrict__ oc) {
  int bid = blockIdx.x;
  const float* src;
  unsigned short* dst;
  int base;
  if (bid < 512) { src = a; dst = oa; base = bid; }
  else if (bid < 1024) { src = b; dst = ob; base = bid - 512; }
  else { src = c; dst = oc; base = bid - 1024; }
  int i = base * 256 + threadIdx.x;
  const float4* p = (const float4*)src + (size_t)i * 2;
  float4 x = p[0], y = p[1];
  float vals[8] = {x.x, x.y, x.z, x.w, y.x, y.y, y.z, y.w};
  union { unsigned short u[8]; uint4 v; } r;
#pragma unroll
  for (int j = 0; j < 8; ++j) r.u[j] = f2bf(vals[j]);
  ((uint4*)dst)[i] = r.v;
}

// ---------------------------------------------------------------- GEMM
// BM=256, BN=128, BK=64, 512 threads / 8 waves (2M x 4N, per-wave 128x32).
// Ring of 3 LDS K-tile slots (A 32KB + B 16KB = 48KB each, 144KB total,
// 1 block/CU, 2 waves/SIMD). Per K-tile j: 2 phases (m-halves), each
// {ds_read_b128 frags | 3 global_load_lds of tile j+2 -> s_barrier ->
//  lgkmcnt(0)+sched_barrier -> setprio(1) 16 MFMA setprio(0) -> s_barrier};
// counted s_waitcnt vmcnt(6) once per K-tile BEFORE the iter-end barrier
// (tile j+2's 6 loads stay in flight => tile j+1 landed, and the barrier
// publishes the guarantee to all waves). Tail: vmcnt(0) when j+2==NT.
// B-frags read once per K-tile, held in regs across both phases.
// LDS swizzle (round-3 formula, measured 0 conflicts): 128B rows,
// granule bits (byte 4..6) XOR (row&7); staging pre-swizzles the GLOBAL
// source column, gload_lds dest stays linear (rule #21).
//
// C = A * B^T over the K axis.
// MODE 0: proj  A=xb[8192][1024]  B=Wqk[2048][1024]  C=QK bf16 [8192][2048]
// MODE 1: Vt    A=Wv[1024][1024]  B=xb[8192][1024]   C=Vt bf16 [1024][8192]
// MODE 2: S     A=QK(Q part)      B=QK+1024 (K part) C=S  bf16 [8192][2048]
//               288 causal blocks: qt 0..7 (256-row) x jt<=2qt+1 (128-col)
// MODE 3: PV    A=P[8192][2048]   B=Vt[1024][8192]   C=Out f32 [8192][1024]
//               NT=(qt+1)*4, longest-first; B col offset b*2048
template <int MODE>
__device__ __forceinline__ void gemm_body(const unsigned short* __restrict__ A,
                                          const unsigned short* __restrict__ B,
                                          void* __restrict__ Cv) {
  constexpr int LDA = (MODE <= 1) ? 1024 : 2048;
  constexpr int LDB = (MODE <= 1) ? 1024 : (MODE == 2 ? 2048 : 8192);
  constexpr int LDC =
      (MODE == 0) ? 2048 : (MODE == 1 ? 8192 : (MODE == 2 ? 2048 : 1024));
  constexpr int NWG = (MODE == 0) ? 512 : (MODE == 2 ? 288 : 256);

  // XCD-chunked bijective swizzle (NWG % 8 == 0)
  const int wg = ((int)blockIdx.x & 7) * (NWG >> 3) + ((int)blockIdx.x >> 3);

  int arow, brow, NT = 16, kb = 0;
  size_t cbase;
  if constexpr (MODE == 0) {
    int bm = wg & 31, bn = wg >> 5;
    arow = bm * 256; brow = bn * 128;
    cbase = (size_t)arow * LDC + bn * 128;
  } else if constexpr (MODE == 1) {
    int bm = wg & 3, bn = wg >> 2;
    arow = bm * 256; brow = bn * 128;
    cbase = (size_t)arow * LDC + bn * 128;
  } else if constexpr (MODE == 2) {
    int b = wg / 72, e = wg % 72;
    int qt = (int)((sqrtf(4.f * (float)e + 1.f) - 1.f) * 0.5f);
    if ((qt + 1) * (qt + 2) <= e) ++qt;
    if (qt * (qt + 1) > e) --qt;
    int jt = e - qt * (qt + 1);
    arow = b * 2048 + qt * 256;
    brow = b * 2048 + jt * 128;
    cbase = (size_t)arow * LDC + jt * 128;
  } else {
    int n = wg & 7, r = wg >> 3;
    int b = r >> 3, qt = 7 - (r & 7);  // longest K-extent first
    arow = b * 2048 + qt * 256;
    brow = n * 128;
    kb = b * 2048;
    NT = (qt + 1) * 4;
    cbase = (size_t)arow * LDC + n * 128;
  }

  __shared__ char lds[3][49152];  // slot: A 32KB @0, B 16KB @32768
  const int tid = threadIdx.x, lane = tid & 63;
  const int l15 = lane & 15, g = lane >> 4;
  const int w = tid >> 6, wm = w >> 2, wn = w & 3;

  f32x4 acc[8][2] = {};

  // stage load i (A: i=0..3, B: i=0..1) of K-tile t2 into slot
  auto stageA1 = [&](int slot, int t2, int i) {
    int chunk = i * 512 + tid;  // 16B chunk 0..2047
    int row = chunk >> 3;
    int c8 = (chunk & 7) ^ (row & 7);  // pre-swizzled source granule
    gload_lds16(A + (size_t)(arow + row) * LDA + t2 * 64 + c8 * 8,
                &lds[slot][(chunk & ~63) * 16]);
  };
  auto stageB1 = [&](int slot, int t2, int i) {
    int chunk = i * 512 + tid;  // 0..1023
    int row = chunk >> 3;
    int c8 = (chunk & 7) ^ (row & 7);
    gload_lds16(B + (size_t)(brow + row) * LDB + kb + t2 * 64 + c8 * 8,
                &lds[slot][32768 + (chunk & ~63) * 16]);
  };
  auto lda_frag = [&](int slot, int mt, int kk) -> bf16x8 {
    int row = wm * 128 + mt * 16 + l15;
    int byte = row * 128 + ((kk * 64 + g * 16) ^ ((l15 & 7) << 4));
    return *(const bf16x8*)&lds[slot][byte];
  };
  auto ldb_frag = [&](int slot, int n2, int kk) -> bf16x8 {
    int row = wn * 32 + n2 * 16 + l15;
    int byte = 32768 + row * 128 + ((kk * 64 + g * 16) ^ ((l15 & 7) << 4));
    return *(const bf16x8*)&lds[slot][byte];
  };

  // prologue: stage tiles 0 and 1; vmcnt(6) => tile 0 landed
#pragma unroll
  for (int i = 0; i < 4; ++i) stageA1(0, 0, i);
#pragma unroll
  for (int i = 0; i < 2; ++i) stageB1(0, 0, i);
#pragma unroll
  for (int i = 0; i < 4; ++i) stageA1(1, 1, i);
#pragma unroll
  for (int i = 0; i < 2; ++i) stageB1(1, 1, i);
  asm volatile("s_waitcnt vmcnt(6)" ::: "memory");
  __builtin_amdgcn_s_barrier();

  int slot = 0;
  for (int j = 0; j < NT; ++j) {
    const int ss = (slot >= 1) ? slot - 1 : 2;  // (j+2)%3
    const bool st = (j + 2) < NT;
    // ---- phase 0: m-half 0 (B frags read once, held across phases) ----
    bf16x8 bv[2][2], af[4][2];
#pragma unroll
    for (int n2 = 0; n2 < 2; ++n2)
#pragma unroll
      for (int kk = 0; kk < 2; ++kk) bv[n2][kk] = ldb_frag(slot, n2, kk);
#pragma unroll
    for (int mt = 0; mt < 4; ++mt)
#pragma unroll
      for (int kk = 0; kk < 2; ++kk) af[mt][kk] = lda_frag(slot, mt, kk);
    if (st) { stageA1(ss, j + 2, 0); stageA1(ss, j + 2, 1); stageA1(ss, j + 2, 2); }
    __builtin_amdgcn_s_barrier();
    asm volatile("s_waitcnt lgkmcnt(0)" ::: "memory");
    __builtin_amdgcn_sched_barrier(0);
    __builtin_amdgcn_s_setprio(1);
#pragma unroll
    for (int mt = 0; mt < 4; ++mt)
#pragma unroll
      for (int n2 = 0; n2 < 2; ++n2)
#pragma unroll
        for (int kk = 0; kk < 2; ++kk)
          acc[mt][n2] = __builtin_amdgcn_mfma_f32_16x16x32_bf16(
              af[mt][kk], bv[n2][kk], acc[mt][n2], 0, 0, 0);
    __builtin_amdgcn_s_setprio(0);
    __builtin_amdgcn_s_barrier();
    // ---- phase 1: m-half 1 (reuse held bv) ----
#pragma unroll
    for (int mt = 0; mt < 4; ++mt)
#pragma unroll
      for (int kk = 0; kk < 2; ++kk) af[mt][kk] = lda_frag(slot, 4 + mt, kk);
    if (st) { stageA1(ss, j + 2, 3); stageB1(ss, j + 2, 0); stageB1(ss, j + 2, 1); }
    __builtin_amdgcn_s_barrier();
    asm volatile("s_waitcnt lgkmcnt(0)" ::: "memory");
    __builtin_amdgcn_sched_barrier(0);
    __builtin_amdgcn_s_setprio(1);
#pragma unroll
    for (int mt = 0; mt < 4; ++mt)
#pragma unroll
      for (int n2 = 0; n2 < 2; ++n2)
#pragma unroll
        for (int kk = 0; kk < 2; ++kk)
          acc[4 + mt][n2] = __builtin_amdgcn_mfma_f32_16x16x32_bf16(
              af[mt][kk], bv[n2][kk], acc[4 + mt][n2], 0, 0, 0);
    __builtin_amdgcn_s_setprio(0);
    if (st) {
      asm volatile("s_waitcnt vmcnt(6)" ::: "memory");  // tile j+1 landed
    } else if (j + 2 == NT) {
      asm volatile("s_waitcnt vmcnt(0)" ::: "memory");  // tail drain
    }
    __builtin_amdgcn_s_barrier();  // publishes the vmcnt guarantee
    slot = (slot == 2) ? 0 : slot + 1;
  }

#pragma unroll
  for (int mt = 0; mt < 8; ++mt) {
#pragma unroll
    for (int r = 0; r < 4; ++r) {
      int ro = wm * 128 + mt * 16 + g * 4 + r;
      int co = wn * 32 + l15;
      if constexpr (MODE == 3) {
        float* Cp = (float*)Cv + cbase + (size_t)ro * LDC + co;
        Cp[0] = acc[mt][0][r];
        Cp[16] = acc[mt][1][r];
      } else {
        unsigned short* Cp = (unsigned short*)Cv + cbase + (size_t)ro * LDC + co;
        Cp[0] = f2bf(acc[mt][0][r]);
        Cp[16] = f2bf(acc[mt][1][r]);
      }
    }
  }
}

__global__ __launch_bounds__(512, 2) void gemm_proj(
    const unsigned short* __restrict__ A, const unsigned short* __restrict__ B,
    void* __restrict__ C) { gemm_body<0>(A, B, C); }
__global__ __launch_bounds__(512, 2) void gemm_vt(
    const unsigned short* __restrict__ A, const unsigned short* __restrict__ B,
    void* __restrict__ C) { gemm_body<1>(A, B, C); }
__global__ __launch_bounds__(512, 2) void gemm_s(
    const unsigned short* __restrict__ A, const unsigned short* __restrict__ B,
    void* __restrict__ C) { gemm_body<2>(A, B, C); }
__global__ __launch_bounds__(512, 2) void gemm_pv(
    const unsigned short* __restrict__ A, const unsigned short* __restrict__ B,
    void* __restrict__ C) { gemm_body<3>(A, B, C); }

// ---------------------------------------------------------------- softmax
// In-place row softmax over the causal prefix of S [8192][2048] bf16.
// Folds the 1/sqrt(d) scale (as exp2) and the 1/l normalization into P.
// Zero-pads cols q+1 .. kmax-1, kmax = 256-tile boundary (PV BM=256).
__global__ __launch_bounds__(256) void softmax_kernel(
    unsigned short* __restrict__ S) {
  const int r = blockIdx.x * 4 + (threadIdx.x >> 6);
  const int lane = threadIdx.x & 63;
  const int q = r & 2047;
  unsigned short* row = S + (size_t)r * 2048;
  const int klen = q + 1;
  const int kmax = ((q >> 8) + 1) << 8;  // padded extent (256-tile boundary)

  float v[4][8];
  float m = -__builtin_inff();
#pragma unroll
  for (int it = 0; it < 4; ++it) {
    int base = (lane + it * 64) * 8;
    if (base < klen) {
      bf16x8 u = *(const bf16x8*)(row + base);
#pragma unroll
      for (int e = 0; e < 8; ++e) {
        float f = bf2f((unsigned short)u[e]) * CSCALE;
        v[it][e] = (base + e <= q) ? f : -__builtin_inff();
        m = fmaxf(m, v[it][e]);
      }
    } else {
#pragma unroll
      for (int e = 0; e < 8; ++e) v[it][e] = -__builtin_inff();
    }
  }
#pragma unroll
  for (int s = 1; s < 64; s <<= 1) m = fmaxf(m, __shfl_xor(m, s));

  float lsum = 0.f;
#pragma unroll
  for (int it = 0; it < 4; ++it)
#pragma unroll
    for (int e = 0; e < 8; ++e) {
      float p = exp2f(v[it][e] - m);
      v[it][e] = p;
      lsum += p;
    }
#pragma unroll
  for (int s = 1; s < 64; s <<= 1) lsum += __shfl_xor(lsum, s);
  float inv = 1.0f / lsum;

#pragma unroll
  for (int it = 0; it < 4; ++it) {
    int base = (lane + it * 64) * 8;
    if (base < kmax) {
      union { unsigned short u[8]; uint4 x; } o;
#pragma unroll
      for (int e = 0; e < 8; ++e) o.u[e] = f2bf(v[it][e] * inv);
      *(uint4*)(row + base) = o.x;
    }
  }
}

// ---------------------------------------------------------------- launch
extern "C" void kernel_launch(void* const* d_in, const int* in_sizes, int n_in,
                              void* d_out, int out_size, void* d_ws,
                              size_t ws_size, hipStream_t stream) {
  const float* x = (const float*)d_in[0];
  const float* Wq = (const float*)d_in[1];
  const float* Wk = (const float*)d_in[2];
  const float* Wv = (const float*)d_in[3];
  unsigned short* ws = (unsigned short*)d_ws;
  // ws layout (bf16 elements):
  //   xb   @ 0    : 8M  (16 MB)   x as bf16 [8192][1024]
  //   Wqk  @ 8M   : 2M  ( 4 MB)   [Wq;Wk] bf16 [2048][1024]
  //   Wvb  @ 10M  : 1M  ( 2 MB)   Wv bf16 [1024][1024]
  //   QKb  @ 11M  : 16M (32 MB)   [Q|K] bf16 [8192][2048]
  //   Vtb  @ 27M  : 8M  (16 MB)   V^T bf16 [1024][8192]
  //   S/P  @ 35M  : 16M (32 MB)   scores -> probs bf16 [8192][2048]
  unsigned short* xb = ws;
  unsigned short* Wqk = ws + (size_t)(8u << 20);
  unsigned short* Wvb = ws + (size_t)(10u << 20);
  unsigned short* QKb = ws + (size_t)(11u << 20);
  unsigned short* Vtb = ws + (size_t)(27u << 20);
  unsigned short* Sb = ws + (size_t)(35u << 20);

  cvt_kernel<<<4096, 256, 0, stream>>>(x, xb, 1048576);
  cvt3_kernel<<<1536, 256, 0, stream>>>(Wq, Wk, Wv, Wqk,
                                        Wqk + (size_t)(1u << 20), Wvb);
  // QK = xb @ [Wq;Wk]^T : [8192 x 2048]
  gemm_proj<<<512, 512, 0, stream>>>(xb, Wqk, QKb);
  // Vt = Wv @ xb^T : [1024 x 8192]
  gemm_vt<<<256, 512, 0, stream>>>(Wvb, xb, Vtb);
  // S = Q @ K^T (causal: 256-row q-tiles x 128-col k-tiles, jt <= 2qt+1)
  gemm_s<<<288, 512, 0, stream>>>(QKb, QKb + 1024, Sb);
  // P = softmax(S * scale) / l, zero-padded to 256-tile boundary
  softmax_kernel<<<2048, 256, 0, stream>>>(Sb);
  // Out = P @ V : [8192 x 1024] fp32
  gemm_pv<<<256, 512, 0, stream>>>(Sb, Vtb, (float*)d_out);
}

// Round 6
// 246.231 us; speedup vs baseline: 1.8421x; 1.0118x over previous
//
#include <hip/hip_runtime.h>
#include <cstdint>
#include <cstddef>
#include <cmath>

typedef __attribute__((ext_vector_type(8))) short bf16x8;
typedef __attribute__((ext_vector_type(4))) float f32x4;

#define CSCALE 0.045084220027780106f /* log2(e) / sqrt(1024) */

__device__ __forceinline__ void gload_lds16(const void* g, void* l) {
  __builtin_amdgcn_global_load_lds(
      (const __attribute__((address_space(1))) unsigned int*)g,
      (__attribute__((address_space(3))) unsigned int*)l, 16, 0, 0);
}

__device__ __forceinline__ unsigned short f2bf(float f) {
  unsigned int u = __float_as_uint(f);
  return (unsigned short)((u + 0x7FFFu + ((u >> 16) & 1u)) >> 16);
}

__device__ __forceinline__ float bf2f(unsigned short u) {
  return __uint_as_float((unsigned int)u << 16);
}

// ---------------------------------------------------------------- convert
__global__ void cvt_kernel(const float* __restrict__ in,
                           unsigned short* __restrict__ out, int n8) {
  int i = blockIdx.x * blockDim.x + threadIdx.x;
  if (i >= n8) return;
  const float4* p = (const float4*)in + (size_t)i * 2;
  float4 a = p[0], b = p[1];
  float vals[8] = {a.x, a.y, a.z, a.w, b.x, b.y, b.z, b.w};
  union { unsigned short u[8]; uint4 v; } r;
#pragma unroll
  for (int j = 0; j < 8; ++j) r.u[j] = f2bf(vals[j]);
  ((uint4*)out)[i] = r.v;
}

__global__ void cvt3_kernel(const float* __restrict__ a,
                            const float* __restrict__ b,
                            const float* __restrict__ c,
                            unsigned short* __restrict__ oa,
                            unsigned short* __restrict__ ob,
                            unsigned short* __restrict__ oc) {
  int bid = blockIdx.x;
  const float* src;
  unsigned short* dst;
  int base;
  if (bid < 512) { src = a; dst = oa; base = bid; }
  else if (bid < 1024) { src = b; dst = ob; base = bid - 512; }
  else { src = c; dst = oc; base = bid - 1024; }
  int i = base * 256 + threadIdx.x;
  const float4* p = (const float4*)src + (size_t)i * 2;
  float4 x = p[0], y = p[1];
  float vals[8] = {x.x, x.y, x.z, x.w, y.x, y.y, y.z, y.w};
  union { unsigned short u[8]; uint4 v; } r;
#pragma unroll
  for (int j = 0; j < 8; ++j) r.u[j] = f2bf(vals[j]);
  ((uint4*)dst)[i] = r.v;
}

// ---------------------------------------------------------------- GEMM
// m201-geometry port: BM=BN=256, BK=64, 512 thr / 8 waves (2M x 4N,
// per-wave 128x64, acc 8x4 f32x4). LDS: 2 dbuf x (A 32K + B 32K) = 128 KB.
// Per K-tile j (dbuf d=j&1; tile j+2 staged into SAME dbuf region-by-region
// after that region's reads are barrier-published):
//   P0: R0 = af_m0(8) + bv01(4) ds_read_b128; lgkm(0)+schedbar+bar;
//       stage A-ops 0,2 (j+2); issue R1 = bv23(4); setprio MFMA m0xn01 (16)
//   P1: lgkm(0)+schedbar+bar; stage B-ops 0..3; issue R2 = af_m1(8);
//       setprio MFMA m0xn23 (16)
//   P2: lgkm(0)+schedbar+bar; stage A-ops 1,3; setprio MFMA m1xn23 + m1xn01
//       (32); vmcnt(8) [= tile j+2's 8 loads in flight => j+1 landed]; bar
// Never drains vmcnt to 0 until the tail. Reads for the next cluster are
// issued under the current MFMA cluster (T3/T4); T5 setprio per cluster.
// LDS swizzle: round-5 formula, measured 0 bank conflicts. 128-B rows;
// read granule (kk*4+g) ^ (l15&7); staging pre-swizzles the GLOBAL source
// granule c8 = (chunk&7)^(row&7), gload_lds dest linear (rule #21).
//
// C = A * B^T over the K axis.
// MODE 0: proj A=xb[8192][1024]  B=Wqk[2048][1024]  C=QK bf16 [8192][2048]
// MODE 1: Vt   A=Wv[1024][1024]  B=xb[8192][1024]   C=Vt bf16 [1024][8192]
// MODE 2: S    A=QK(Q)           B=QK+1024 (K)      C=S  bf16 [8192][2048]
//              144 causal blocks: 256^2 tiles, jt<=qt
// MODE 3: PV   A=P[8192][2048]   B=Vt[1024][8192]   C=Out f32 [8192][1024]
//              split-K: qt<4 one unit; qt>=4 two halves (half1 -> Cpart)
template <int MODE>
__device__ __forceinline__ void gemm_body(const unsigned short* __restrict__ A,
                                          const unsigned short* __restrict__ B,
                                          void* __restrict__ Cv,
                                          float* __restrict__ Cpart) {
  constexpr int LDA = (MODE <= 1) ? 1024 : 2048;
  constexpr int LDB = (MODE <= 1) ? 1024 : (MODE == 2 ? 2048 : 8192);
  constexpr int LDC =
      (MODE == 0) ? 2048 : (MODE == 1 ? 8192 : (MODE == 2 ? 2048 : 1024));

  int arow, brow, NT = 16, kA = 0, kB = 0;
  size_t cbase;
  bool toPart = false;
  if constexpr (MODE == 0) {
    int bm = blockIdx.x & 31, bn = blockIdx.x >> 5;
    arow = bm * 256; brow = bn * 256;
    cbase = (size_t)arow * LDC + bn * 256;
  } else if constexpr (MODE == 1) {
    int bm = blockIdx.x & 3, bn = blockIdx.x >> 2;
    arow = bm * 256; brow = bn * 256;
    cbase = (size_t)arow * LDC + bn * 256;
  } else if constexpr (MODE == 2) {
    int b = blockIdx.x / 36, e = blockIdx.x % 36;
    int qt = (int)((sqrtf(8.f * (float)e + 1.f) - 1.f) * 0.5f);
    if ((qt + 1) * (qt + 2) / 2 <= e) ++qt;
    if (qt * (qt + 1) / 2 > e) --qt;
    int jt = e - qt * (qt + 1) / 2;
    arow = b * 2048 + qt * 256;
    brow = b * 2048 + jt * 256;
    cbase = (size_t)arow * LDC + jt * 256;
  } else {
    int bn = blockIdx.x & 3, u = blockIdx.x >> 2;
    int b = u / 12, ub = u % 12;
    int qt, half;
    if (ub < 4) { qt = ub; half = -1; NT = (qt + 1) * 4; kA = 0; }
    else { int idx = ub - 4; qt = 4 + (idx >> 1); half = idx & 1;
           NT = (qt + 1) * 2; kA = half * NT * 64; }
    arow = b * 2048 + qt * 256;
    brow = bn * 256;
    kB = b * 2048 + kA;
    toPart = (half == 1);
    cbase = toPart ? ((size_t)(b * 1024 + (qt - 4) * 256) * 1024 + bn * 256)
                   : ((size_t)arow * 1024 + bn * 256);
  }

  __shared__ char lds[2][65536];  // dbuf: A 32KB @0, B 32KB @32768
  const int tid = threadIdx.x, lane = tid & 63;
  const int l15 = lane & 15, g = lane >> 4;
  const int w = tid >> 6, wm = w >> 2, wn = w & 3;

  f32x4 acc[8][4] = {};

  // stage op i (rows i*64..i*64+63) of K-tile t into dbuf d; 1 gload/thread
  auto stageA = [&](int d, int t, int i) {
    int chunk = i * 512 + tid;  // 16B chunk
    int row = chunk >> 3;
    int c8 = (chunk & 7) ^ (row & 7);
    gload_lds16(A + (size_t)(arow + row) * LDA + kA + t * 64 + c8 * 8,
                &lds[d][(chunk & ~63) * 16]);
  };
  auto stageB = [&](int d, int t, int i) {
    int chunk = i * 512 + tid;
    int row = chunk >> 3;
    int c8 = (chunk & 7) ^ (row & 7);
    gload_lds16(B + (size_t)(brow + row) * LDB + kB + t * 64 + c8 * 8,
                &lds[d][32768 + (chunk & ~63) * 16]);
  };
  auto lda_frag = [&](int d, int mt, int kk) -> bf16x8 {
    int row = wm * 128 + mt * 16 + l15;
    int byte = row * 128 + (((kk * 4 + g) ^ (l15 & 7)) << 4);
    return *(const bf16x8*)&lds[d][byte];
  };
  auto ldb_frag = [&](int d, int nf, int kk) -> bf16x8 {
    int row = wn * 64 + nf * 16 + l15;
    int byte = 32768 + row * 128 + (((kk * 4 + g) ^ (l15 & 7)) << 4);
    return *(const bf16x8*)&lds[d][byte];
  };

  // prologue: stage tiles 0 (dbuf0) and 1 (dbuf1); vmcnt(8) => tile 0 landed
#pragma unroll
  for (int i = 0; i < 4; ++i) stageA(0, 0, i);
#pragma unroll
  for (int i = 0; i < 4; ++i) stageB(0, 0, i);
#pragma unroll
  for (int i = 0; i < 4; ++i) stageA(1, 1, i);
#pragma unroll
  for (int i = 0; i < 4; ++i) stageB(1, 1, i);
  asm volatile("s_waitcnt vmcnt(8)" ::: "memory");
  __builtin_amdgcn_s_barrier();

  for (int j = 0; j < NT; ++j) {
    const int d = j & 1;
    const bool st = (j + 2) < NT;
    bf16x8 af0[4][2], af1[4][2], bv[4][2];
    // ---- P0: R0 = af_m0 + bv01 ----
#pragma unroll
    for (int mt = 0; mt < 4; ++mt)
#pragma unroll
      for (int kk = 0; kk < 2; ++kk) af0[mt][kk] = lda_frag(d, mt, kk);
#pragma unroll
    for (int nf = 0; nf < 2; ++nf)
#pragma unroll
      for (int kk = 0; kk < 2; ++kk) bv[nf][kk] = ldb_frag(d, nf, kk);
    asm volatile("s_waitcnt lgkmcnt(0)" ::: "memory");
    __builtin_amdgcn_sched_barrier(0);
    __builtin_amdgcn_s_barrier();
    if (st) { stageA(d, j + 2, 0); stageA(d, j + 2, 2); }
#pragma unroll
    for (int nf = 2; nf < 4; ++nf)  // R1 = bv23, overlaps MFMA below
#pragma unroll
      for (int kk = 0; kk < 2; ++kk) bv[nf][kk] = ldb_frag(d, nf, kk);
    __builtin_amdgcn_s_setprio(1);
#pragma unroll
    for (int mt = 0; mt < 4; ++mt)
#pragma unroll
      for (int nf = 0; nf < 2; ++nf)
#pragma unroll
        for (int kk = 0; kk < 2; ++kk)
          acc[mt][nf] = __builtin_amdgcn_mfma_f32_16x16x32_bf16(
              af0[mt][kk], bv[nf][kk], acc[mt][nf], 0, 0, 0);
    __builtin_amdgcn_s_setprio(0);
    // ---- P1 ----
    asm volatile("s_waitcnt lgkmcnt(0)" ::: "memory");
    __builtin_amdgcn_sched_barrier(0);
    __builtin_amdgcn_s_barrier();
    if (st) {
      stageB(d, j + 2, 0); stageB(d, j + 2, 1);
      stageB(d, j + 2, 2); stageB(d, j + 2, 3);
    }
#pragma unroll
    for (int mt = 0; mt < 4; ++mt)  // R2 = af_m1, overlaps MFMA below
#pragma unroll
      for (int kk = 0; kk < 2; ++kk) af1[mt][kk] = lda_frag(d, 4 + mt, kk);
    __builtin_amdgcn_s_setprio(1);
#pragma unroll
    for (int mt = 0; mt < 4; ++mt)
#pragma unroll
      for (int nf = 2; nf < 4; ++nf)
#pragma unroll
        for (int kk = 0; kk < 2; ++kk)
          acc[mt][nf] = __builtin_amdgcn_mfma_f32_16x16x32_bf16(
              af0[mt][kk], bv[nf][kk], acc[mt][nf], 0, 0, 0);
    __builtin_amdgcn_s_setprio(0);
    // ---- P2 ----
    asm volatile("s_waitcnt lgkmcnt(0)" ::: "memory");
    __builtin_amdgcn_sched_barrier(0);
    __builtin_amdgcn_s_barrier();
    if (st) { stageA(d, j + 2, 1); stageA(d, j + 2, 3); }
    __builtin_amdgcn_s_setprio(1);
#pragma unroll
    for (int mt = 0; mt < 4; ++mt)
#pragma unroll
      for (int nf = 0; nf < 4; ++nf)
#pragma unroll
        for (int kk = 0; kk < 2; ++kk)
          acc[4 + mt][nf] = __builtin_amdgcn_mfma_f32_16x16x32_bf16(
              af1[mt][kk], bv[nf][kk], acc[4 + mt][nf], 0, 0, 0);
    __builtin_amdgcn_s_setprio(0);
    if (st) {
      asm volatile("s_waitcnt vmcnt(8)" ::: "memory");  // tile j+1 landed
    } else if (j + 2 == NT) {
      asm volatile("s_waitcnt vmcnt(0)" ::: "memory");  // tail drain
    }
    __builtin_amdgcn_s_barrier();  // publish to all waves
  }

#pragma unroll
  for (int mt = 0; mt < 8; ++mt) {
#pragma unroll
    for (int r = 0; r < 4; ++r) {
      int ro = wm * 128 + mt * 16 + g * 4 + r;
      int co = wn * 64 + l15;
      if constexpr (MODE == 3) {
        float* base = toPart ? Cpart : (float*)Cv;
        float* Cp = base + cbase + (size_t)ro * LDC + co;
#pragma unroll
        for (int nf = 0; nf < 4; ++nf) Cp[nf * 16] = acc[mt][nf][r];
      } else {
        unsigned short* Cp =
            (unsigned short*)Cv + cbase + (size_t)ro * LDC + co;
#pragma unroll
        for (int nf = 0; nf < 4; ++nf) Cp[nf * 16] = f2bf(acc[mt][nf][r]);
      }
    }
  }
}

__global__ __launch_bounds__(512, 2) void gemm_proj(
    const unsigned short* __restrict__ A, const unsigned short* __restrict__ B,
    void* __restrict__ C) { gemm_body<0>(A, B, C, nullptr); }
__global__ __launch_bounds__(512, 2) void gemm_vt(
    const unsigned short* __restrict__ A, const unsigned short* __restrict__ B,
    void* __restrict__ C) { gemm_body<1>(A, B, C, nullptr); }
__global__ __launch_bounds__(512, 2) void gemm_s(
    const unsigned short* __restrict__ A, const unsigned short* __restrict__ B,
    void* __restrict__ C) { gemm_body<2>(A, B, C, nullptr); }
__global__ __launch_bounds__(512, 2) void gemm_pv(
    const unsigned short* __restrict__ A, const unsigned short* __restrict__ B,
    void* __restrict__ C, float* __restrict__ Cpart) {
  gemm_body<3>(A, B, C, Cpart);
}

// fixup: Out rows [b*2048+1024, b*2048+2048) += Part rows [b*1024, ...)
__global__ __launch_bounds__(256) void fixup_kernel(
    float* __restrict__ Out, const float* __restrict__ Part) {
  int j = blockIdx.x * 256 + threadIdx.x;  // one float4 each, 1M total
  int row = j >> 8, c4 = j & 255;
  int b = row >> 10, r = row & 1023;
  float4* o = (float4*)(Out + (size_t)(b * 2048 + 1024 + r) * 1024) + c4;
  const float4* p = (const float4*)(Part + (size_t)row * 1024) + c4;
  float4 a = *o, q = *p;
  a.x += q.x; a.y += q.y; a.z += q.z; a.w += q.w;
  *o = a;
}

// ---------------------------------------------------------------- softmax
// In-place row softmax over the causal prefix of S [8192][2048] bf16.
// Folds the 1/sqrt(d) scale (as exp2) and the 1/l normalization into P.
// Zero-pads cols q+1 .. kmax-1, kmax = 256-tile boundary (PV BM=256).
__global__ __launch_bounds__(256) void softmax_kernel(
    unsigned short* __restrict__ S) {
  const int r = blockIdx.x * 4 + (threadIdx.x >> 6);
  const int lane = threadIdx.x & 63;
  const int q = r & 2047;
  unsigned short* row = S + (size_t)r * 2048;
  const int klen = q + 1;
  const int kmax = ((q >> 8) + 1) << 8;

  float v[4][8];
  float m = -__builtin_inff();
#pragma unroll
  for (int it = 0; it < 4; ++it) {
    int base = (lane + it * 64) * 8;
    if (base < klen) {
      bf16x8 u = *(const bf16x8*)(row + base);
#pragma unroll
      for (int e = 0; e < 8; ++e) {
        float f = bf2f((unsigned short)u[e]) * CSCALE;
        v[it][e] = (base + e <= q) ? f : -__builtin_inff();
        m = fmaxf(m, v[it][e]);
      }
    } else {
#pragma unroll
      for (int e = 0; e < 8; ++e) v[it][e] = -__builtin_inff();
    }
  }
#pragma unroll
  for (int s = 1; s < 64; s <<= 1) m = fmaxf(m, __shfl_xor(m, s));

  float lsum = 0.f;
#pragma unroll
  for (int it = 0; it < 4; ++it)
#pragma unroll
    for (int e = 0; e < 8; ++e) {
      float p = exp2f(v[it][e] - m);
      v[it][e] = p;
      lsum += p;
    }
#pragma unroll
  for (int s = 1; s < 64; s <<= 1) lsum += __shfl_xor(lsum, s);
  float inv = 1.0f / lsum;

#pragma unroll
  for (int it = 0; it < 4; ++it) {
    int base = (lane + it * 64) * 8;
    if (base < kmax) {
      union { unsigned short u[8]; uint4 x; } o;
#pragma unroll
      for (int e = 0; e < 8; ++e) o.u[e] = f2bf(v[it][e] * inv);
      *(uint4*)(row + base) = o.x;
    }
  }
}

// ---------------------------------------------------------------- launch
extern "C" void kernel_launch(void* const* d_in, const int* in_sizes, int n_in,
                              void* d_out, int out_size, void* d_ws,
                              size_t ws_size, hipStream_t stream) {
  const float* x = (const float*)d_in[0];
  const float* Wq = (const float*)d_in[1];
  const float* Wk = (const float*)d_in[2];
  const float* Wv = (const float*)d_in[3];
  unsigned short* ws = (unsigned short*)d_ws;
  // ws layout (bf16 elements):
  //   xb   @ 0    : 8M  (16 MB)   x bf16 [8192][1024]; region REUSED as
  //                               PV split-K partial (f32 [4096][1024]) later
  //   Wqk  @ 8M   : 2M  ( 4 MB)
  //   Wvb  @ 10M  : 1M  ( 2 MB)
  //   QKb  @ 11M  : 16M (32 MB)   [Q|K] bf16 [8192][2048]
  //   Vtb  @ 27M  : 8M  (16 MB)   V^T bf16 [1024][8192]
  //   S/P  @ 35M  : 16M (32 MB)   scores -> probs bf16 [8192][2048]
  unsigned short* xb = ws;
  unsigned short* Wqk = ws + (size_t)(8u << 20);
  unsigned short* Wvb = ws + (size_t)(10u << 20);
  unsigned short* QKb = ws + (size_t)(11u << 20);
  unsigned short* Vtb = ws + (size_t)(27u << 20);
  unsigned short* Sb = ws + (size_t)(35u << 20);
  float* Ppart = (float*)d_ws;  // overlays xb (dead by PV time)

  cvt_kernel<<<4096, 256, 0, stream>>>(x, xb, 1048576);
  cvt3_kernel<<<1536, 256, 0, stream>>>(Wq, Wk, Wv, Wqk,
                                        Wqk + (size_t)(1u << 20), Wvb);
  // QK = xb @ [Wq;Wk]^T : [8192 x 2048], 256 blocks (1/CU)
  gemm_proj<<<256, 512, 0, stream>>>(xb, Wqk, QKb);
  // Vt = Wv @ xb^T : [1024 x 8192]
  gemm_vt<<<128, 512, 0, stream>>>(Wvb, xb, Vtb);
  // S = Q @ K^T (causal 256^2 tiles, jt <= qt), batched over b
  gemm_s<<<144, 512, 0, stream>>>(QKb, QKb + 1024, Sb);
  // P = softmax(S * scale) / l, zero-padded to 256-tile boundary
  softmax_kernel<<<2048, 256, 0, stream>>>(Sb);
  // Out = P @ V : [8192 x 1024] fp32 (split-K halves for qt>=4)
  gemm_pv<<<192, 512, 0, stream>>>(Sb, Vtb, (float*)d_out, Ppart);
  fixup_kernel<<<4096, 256, 0, stream>>>((float*)d_out, Ppart);
}